// Round 8
// baseline (202.510 us; speedup 1.0000x reference)
//
#include <hip/hip_runtime.h>
#include <hip/hip_bf16.h>
#include <cstdint>

// Problem constants: T=512 timesteps/slots, B=64 batch, E=512 embed.
#define TT 512
#define BB 64
#define EE 512

typedef short bf16x8 __attribute__((ext_vector_type(8)));   // 8 bf16 = 4 VGPRs
typedef float f32x4  __attribute__((ext_vector_type(4)));   // MFMA C/D frag

// RNE pack of (a -> low16, b -> high16); compiler emits v_cvt_pk_bf16_f32.
static __device__ __forceinline__ unsigned bpack(float a, float b) {
    union { __hip_bfloat162 h; unsigned u; } cv;
    cv.h = __float22bfloat162_rn(make_float2(a, b));
    return cv.u;
}

// Barrier that does NOT drain vmcnt: LDS traffic is made visible
// (lgkmcnt(0)), in-flight global register prefetches stay outstanding.
static __device__ __forceinline__ void barrier_lds_only() {
    asm volatile("s_waitcnt lgkmcnt(0)" ::: "memory");
    __builtin_amdgcn_s_barrier();
}

// ---------------------------------------------------------------------------
// R1 structure (best measured: 46.2 us) + bank-floor B-fill.
//   Cross-round evidence: sbuf-2bar (R1) == dbuf-1bar (R5) == 8-wave (R7)
//   at ~2750 cy/interval -> schedule-insensitive; LDS pipe is the binding
//   resource (~50 KB/interval x 4 blocks/CU ~ 65-70% busy incl. conflicts).
//   Bank audit of stride-40: A-writes floor, frag reads floor; B-WRITES
//   (rows 2*lane) hit only banks {0,8,16,24} -> depth 16 = 2x floor. This
//   version remaps B-fill: thread owns e=tid&127, kh=tid>>7 (16 scalar
//   loads, same bytes, coalesced) -> write rows = consecutive lane ->
//   bases (20*lane)%32 = all 8 mult-of-4 groups -> depth 8 = FLOOR.
//
//   wave-0 prologue: queue scan (closed form, max-plus wave scan) -> Rs/CUs.
//     Q(t) = relu(Q(t-1) - u_t) + d_t,  CU(t) = sum u,  R(t) = Q(t) + CU(t)
//   main: out[t,b,e] = sum_i C[t,i] * V[i,b,e],
//     C[t,i] = min(relu(R_i-CU_t),1) - min(relu(R_{i-1}-CU_t),1)  (0 for i>t)
//
// 128m x 128n block tile, BK=32, 4 waves (2x2), 64x64/wave, acc[4][4].
// Triangular: tile MI needs kiters = 4(MI+1). MI = (g+s)&3 -> a CU's 4
// resident blocks (ids 256 apart) get MI {0,1,2,3}: per-CU work balanced
// at 40 intervals. Grid 1024 x 256 th, 4 blocks/CU (LDS 24.5 KB).
// ---------------------------------------------------------------------------
__global__ __launch_bounds__(256, 4) void gemm_fused_kernel(
        const float* __restrict__ V,    // [T(i)][B][E]
        const float* __restrict__ U,    // [T][B]
        const float* __restrict__ D,    // [T][B]
        float* __restrict__ out) {      // [T(t)][B][E]
    const int id  = blockIdx.x;
    const int xcd = id & 7;
    const int g   = id >> 8;            // 0..3 stride-256 dispatch group
    const int s   = (id >> 3) & 31;     // 0..31
    const int MI  = (g + s) & 3;        // balanced MI per CU
    const int b   = xcd + 8 * (s & 7);  // b % 8 == xcd
    const int n0  = (s >> 3) * 128;
    const int m0  = MI * 128;
    const int kiters = 4 * (MI + 1);    // k0 < m0 + 128

    __shared__ __align__(16) unsigned short As[128 * 40];  // [t][i] stride 40
    __shared__ __align__(16) unsigned short Bs[128 * 40];  // [e][i] stride 40
    __shared__ __align__(16) float Rs[TT];
    __shared__ __align__(16) float CUs[TT];

    const int tid  = threadIdx.x;
    const int wave = tid >> 6;
    const int lane = tid & 63;

    // A-fill: thread owns row a_t, 16 contiguous i.
    const int a_t  = tid >> 1;            // 0..127
    const int a_i0 = (tid & 1) * 16;      // 0 or 16
    // B-fill: thread owns ONE e-row, 16 consecutive k (bank-floor writes).
    const int b_e  = tid & 127;           // e-col 0..127
    const int b_kh = tid >> 7;            // k-half: 0 or 1 (16 k each)
    // Fragments: 2x2 waves, 64x64 per wave.
    const int wm   = (wave >> 1) * 64;
    const int wn   = (wave & 1) * 64;
    const int frow = lane & 15;
    const int quad = lane >> 4;

    const float* Vb = V + (size_t)b * EE + n0 + b_e;   // + k*(BB*EE)

    // Prefetch chunk 0 (16 scalar loads, 512-B coalesced per wave pair);
    // latency hides under the scan.
    float v[16];
    {
        const float* vp = Vb + (size_t)(b_kh * 16) * (BB * EE);
        #pragma unroll
        for (int r = 0; r < 16; ++r)
            v[r] = vp[(size_t)r * (BB * EE)];
    }

    // ---- In-block scan (wave 0 only): R/CU for batch b into LDS ----
    if (wave == 0) {
        float u[8], d[8];
        #pragma unroll
        for (int j = 0; j < 8; ++j) {
            u[j] = U[(lane * 8 + j) * BB + b];
            d[j] = D[(lane * 8 + j) * BB + b];
        }
        float A = 0.f, Bv = -1e30f, S = 0.f;
        #pragma unroll
        for (int j = 0; j < 8; ++j) {
            const float a = d[j] - u[j];
            Bv = fmaxf(Bv + a, d[j]);
            A += a;
            S += u[j];
        }
        #pragma unroll
        for (int off = 1; off < 64; off <<= 1) {
            const float Ap = __shfl_up(A, off);
            const float Bp = __shfl_up(Bv, off);
            const float Sp = __shfl_up(S, off);
            if (lane >= off) {
                Bv = fmaxf(Bp + A, Bv);
                A  = A + Ap;
                S  = S + Sp;
            }
        }
        float Aex = __shfl_up(A, 1), Bex = __shfl_up(Bv, 1), Sex = __shfl_up(S, 1);
        if (lane == 0) { Aex = 0.f; Bex = -1e30f; Sex = 0.f; }
        float Q  = fmaxf(Aex, Bex);
        float cu = Sex;
        float rv[8], cv[8];
        #pragma unroll
        for (int j = 0; j < 8; ++j) {
            cu += u[j];
            Q = fmaxf(Q - u[j], 0.f) + d[j];
            rv[j] = Q + cu;
            cv[j] = cu;
        }
        *(float4*)(Rs  + lane * 8)     = make_float4(rv[0], rv[1], rv[2], rv[3]);
        *(float4*)(Rs  + lane * 8 + 4) = make_float4(rv[4], rv[5], rv[6], rv[7]);
        *(float4*)(CUs + lane * 8)     = make_float4(cv[0], cv[1], cv[2], cv[3]);
        *(float4*)(CUs + lane * 8 + 4) = make_float4(cv[4], cv[5], cv[6], cv[7]);
    }
    barrier_lds_only();                   // publishes Rs/CUs; v stays in flight

    const float cu_t = CUs[m0 + a_t];

    f32x4 acc[4][4];
    #pragma unroll
    for (int mi = 0; mi < 4; ++mi)
        #pragma unroll
        for (int ni = 0; ni < 4; ++ni)
            acc[mi][ni] = f32x4{0.f, 0.f, 0.f, 0.f};

    for (int kk = 0; kk < kiters; ++kk) {
        const int k0 = kk * 32;

        // ---- A-fill: 16 coeffs from closed form (writes at bank floor) ----
        {
            const int i = k0 + a_i0;
            const float4 r0 = *(const float4*)(Rs + i);
            const float4 r1 = *(const float4*)(Rs + i + 4);
            const float4 r2 = *(const float4*)(Rs + i + 8);
            const float4 r3 = *(const float4*)(Rs + i + 12);
            const float rv[16] = {r0.x, r0.y, r0.z, r0.w, r1.x, r1.y, r1.z, r1.w,
                                  r2.x, r2.y, r2.z, r2.w, r3.x, r3.y, r3.z, r3.w};
            const float prev = (i == 0) ? 0.f : Rs[i - 1];
            float pvp = fminf(fmaxf(prev - cu_t, 0.f), 1.f);
            float c[16];
            if (k0 < m0) {                    // strictly below diagonal
                #pragma unroll
                for (int j = 0; j < 16; ++j) {
                    const float pv = fminf(fmaxf(rv[j] - cu_t, 0.f), 1.f);
                    c[j] = pv - pvp;
                    pvp = pv;
                }
            } else {                          // diagonal chunk: zero for i > t
                const int t = m0 + a_t;
                #pragma unroll
                for (int j = 0; j < 16; ++j) {
                    const float pv = fminf(fmaxf(rv[j] - cu_t, 0.f), 1.f);
                    c[j] = (i + j <= t) ? (pv - pvp) : 0.f;
                    pvp = pv;
                }
            }
            uint4 w0, w1;
            w0.x = bpack(c[0], c[1]);   w0.y = bpack(c[2], c[3]);
            w0.z = bpack(c[4], c[5]);   w0.w = bpack(c[6], c[7]);
            w1.x = bpack(c[8], c[9]);   w1.y = bpack(c[10], c[11]);
            w1.z = bpack(c[12], c[13]); w1.w = bpack(c[14], c[15]);
            *(uint4*)(As + a_t * 40 + a_i0)     = w0;
            *(uint4*)(As + a_t * 40 + a_i0 + 8) = w1;
        }

        // ---- B-fill: one e-row, 16 k; rows = consecutive lane -> floor ----
        {
            uint4 q0, q1;
            q0.x = bpack(v[0], v[1]);   q0.y = bpack(v[2], v[3]);
            q0.z = bpack(v[4], v[5]);   q0.w = bpack(v[6], v[7]);
            q1.x = bpack(v[8], v[9]);   q1.y = bpack(v[10], v[11]);
            q1.z = bpack(v[12], v[13]); q1.w = bpack(v[14], v[15]);
            *(uint4*)(Bs + b_e * 40 + b_kh * 16)     = q0;
            *(uint4*)(Bs + b_e * 40 + b_kh * 16 + 8) = q1;
        }

        // ---- Prefetch next chunk (registers; in flight across barriers) ----
        if (kk + 1 < kiters) {
            const float* vp = Vb + (size_t)((kk + 1) * 32 + b_kh * 16) * (BB * EE);
            #pragma unroll
            for (int r = 0; r < 16; ++r)
                v[r] = vp[(size_t)r * (BB * EE)];
        }

        barrier_lds_only();

        bf16x8 af[4], bf[4];
        #pragma unroll
        for (int mi = 0; mi < 4; ++mi)
            af[mi] = *(const bf16x8*)(As + (wm + mi * 16 + frow) * 40 + quad * 8);
        #pragma unroll
        for (int ni = 0; ni < 4; ++ni)
            bf[ni] = *(const bf16x8*)(Bs + (wn + ni * 16 + frow) * 40 + quad * 8);

        #pragma unroll
        for (int mi = 0; mi < 4; ++mi)
            #pragma unroll
            for (int ni = 0; ni < 4; ++ni)
                acc[mi][ni] = __builtin_amdgcn_mfma_f32_16x16x32_bf16(
                    af[mi], bf[ni], acc[mi][ni], 0, 0, 0);

        barrier_lds_only();
    }

    // Epilogue: C/D layout col=lane&15, row=quad*4+r (m89/m91 verified).
    #pragma unroll
    for (int mi = 0; mi < 4; ++mi) {
        #pragma unroll
        for (int r = 0; r < 4; ++r) {
            const int t = m0 + wm + mi * 16 + quad * 4 + r;
            float* orow = out + ((size_t)t * BB + b) * EE + n0 + wn + frow;
            #pragma unroll
            for (int ni = 0; ni < 4; ++ni)
                orow[ni * 16] = acc[mi][ni][r];
        }
    }
}

extern "C" void kernel_launch(void* const* d_in, const int* in_sizes, int n_in,
                              void* d_out, int out_size, void* d_ws, size_t ws_size,
                              hipStream_t stream) {
    const float* V = (const float*)d_in[0];   // [T,B,E]
    const float* U = (const float*)d_in[1];   // [T,B]
    const float* D = (const float*)d_in[2];   // [T,B]
    float* out = (float*)d_out;               // [T,B,E]

    gemm_fused_kernel<<<dim3(1024), dim3(256), 0, stream>>>(V, U, D, out);
}